// Round 7
// baseline (34563.974 us; speedup 1.0000x reference)
//
#include <hip/hip_runtime.h>
#include <math.h>

// ---------------------------------------------------------------------------
// SimAM-CNN + Mogrifier-LSTM (Round 9): round-6 structure (27.8 ms, proven)
// + lane-interleaved tiled f16 weight layout.
// Round-6 post-mortem: marginal dispatch cost ~1.4us (fusions saved only
// 0.7ms) -> kernels are execution-bound. Audit: per-lane weight rows are
// 512B-8KB strided, so every wave weight load touches 32-64 cache lines.
// Fix: pre-shuffle W into W'[tile][k/4][lane][4] (tile = kernel n-tile) so
// each wave weight load is one contiguous 256-512B transaction. Same values,
// same FMA order -> absmax unchanged.
// ---------------------------------------------------------------------------

typedef unsigned short u16;
typedef _Float16 f16;

#define EPSBN 1e-5f

__device__ __forceinline__ float sigf(float x) { return 1.0f / (1.0f + expf(-x)); }

__device__ __forceinline__ float b2f(u16 u) {
  union { unsigned int i; float f; } v; v.i = ((unsigned int)u) << 16; return v.f;
}
__device__ __forceinline__ u16 f2b(float f) {
  union { float f; unsigned int i; } v; v.f = f;
  unsigned int r = v.i + 0x7FFFu + ((v.i >> 16) & 1u);
  return (u16)(r >> 16);
}

template <typename T> __device__ __forceinline__ float ld1(const T* p);
template <> __device__ __forceinline__ float ld1<float>(const float* p) { return *p; }
template <> __device__ __forceinline__ float ld1<u16>(const u16* p) { return b2f(*p); }
template <typename T> __device__ __forceinline__ void st1(T* p, float v);
template <> __device__ __forceinline__ void st1<float>(float* p, float v) { *p = v; }
template <> __device__ __forceinline__ void st1<u16>(u16* p, float v) { *p = f2b(v); }

__device__ __forceinline__ void ldh4(const f16* p, float* w) {
  union { uint2 u; f16 h[4]; } v; v.u = *(const uint2*)p;
#pragma unroll
  for (int i = 0; i < 4; ++i) w[i] = (float)v.h[i];
}

__device__ __forceinline__ float simam_elem(float xv, float s, float ss) {
  float mu = (s - xv) * (1.0f / 8191.0f);
  float var = (ss - xv * xv - 8191.0f * mu * mu) * (1.0f / 8190.0f);
  float einv = ((xv - mu) * (xv - mu) + 2.0f * var + 0.2f) / (4.0f * (var + 0.1f));
  return xv * sigf(einv);
}

// --------------------------- CNN stage 1 (unchanged) -----------------------
__global__ __launch_bounds__(256) void k_conv1(
    const float* __restrict__ x,
    const float* __restrict__ w1a, const float* __restrict__ b1a,
    const float* __restrict__ g1a, const float* __restrict__ bb1a,
    const float* __restrict__ m1a, const float* __restrict__ v1a,
    const float* __restrict__ w1b, const float* __restrict__ b1b,
    const float* __restrict__ g1b, const float* __restrict__ bb1b,
    const float* __restrict__ m1b, const float* __restrict__ v1b,
    u16* __restrict__ y1u, float* __restrict__ ps1, float* __restrict__ pss1)
{
  __shared__ float xs[6][66];
  __shared__ float a1[32][6][66];
  __shared__ float A1[32], T1[32], S2[32], T2[32];
  __shared__ float reds[4][32], redq[4][32];
  const int tid = threadIdx.x;
  const int b = blockIdx.x, t0 = blockIdx.y * 4;
  if (tid < 32) {
    float s = g1a[tid] * rsqrtf(v1a[tid] + EPSBN);
    A1[tid] = w1a[tid] * s;
    T1[tid] = (b1a[tid] - m1a[tid]) * s + bb1a[tid];
    float s2 = g1b[tid] * rsqrtf(v1b[tid] + EPSBN);
    S2[tid] = s2;
    T2[tid] = (b1b[tid] - m1b[tid]) * s2 + bb1b[tid];
  }
  for (int i = tid; i < 6 * 66; i += 256) {
    int r = i / 66, cc = i - r * 66;
    int t = t0 + r - 1, d = cc - 1;
    float v = 0.f;
    if (t >= 0 && t < 128 && d >= 0 && d < 64) v = x[(b * 128 + t) * 64 + d];
    xs[r][cc] = v;
  }
  __syncthreads();
  for (int i = tid; i < 32 * 6 * 66; i += 256) {
    int c = i / 396;
    int rr = i - c * 396;
    int r = rr / 66, cc = rr - r * 66;
    int t = t0 + r - 1, d = cc - 1;
    float v = 0.f;
    if (t >= 0 && t < 128 && d >= 0 && d < 64)
      v = fmaxf(xs[r][cc] * A1[c] + T1[c], 0.f);
    a1[c][r][cc] = v;
  }
  __syncthreads();
  const int d = tid & 63, tq = tid >> 6, lane = tid & 63;
  float acc[32];
#pragma unroll
  for (int i = 0; i < 32; ++i) acc[i] = 0.f;
#pragma unroll 1
  for (int c1 = 0; c1 < 32; ++c1) {
#pragma unroll
    for (int dt = 0; dt < 3; ++dt) {
      float av0 = a1[c1][tq + dt][d];
      float av1 = a1[c1][tq + dt][d + 1];
      float av2 = a1[c1][tq + dt][d + 2];
#pragma unroll
      for (int c2 = 0; c2 < 32; ++c2) {
        const float* wp = w1b + ((c2 * 32 + c1) * 3 + dt) * 3;  // uniform
        acc[c2] += av0 * wp[0] + av1 * wp[1] + av2 * wp[2];
      }
    }
  }
  const size_t ob = (size_t)b * 32 * 8192 + (size_t)(t0 + tq) * 64 + d;
#pragma unroll
  for (int c2 = 0; c2 < 32; ++c2) {
    float v = fmaxf(acc[c2] * S2[c2] + T2[c2], 0.f);
    y1u[ob + (size_t)c2 * 8192] = f2b(v);
    float s = v, q = v * v;
#pragma unroll
    for (int off = 32; off; off >>= 1) {
      s += __shfl_down(s, off);
      q += __shfl_down(q, off);
    }
    if (lane == 0) { reds[tq][c2] = s; redq[tq][c2] = q; }
  }
  __syncthreads();
  if (tid < 32) {
    float s = (reds[0][tid] + reds[1][tid]) + (reds[2][tid] + reds[3][tid]);
    float q = (redq[0][tid] + redq[1][tid]) + (redq[2][tid] + redq[3][tid]);
    ps1[(size_t)((b * 32 + tid) << 5) + blockIdx.y] = s;
    pss1[(size_t)((b * 32 + tid) << 5) + blockIdx.y] = q;
  }
}

__global__ __launch_bounds__(256) void k_red(
    const float* __restrict__ ps, const float* __restrict__ pss,
    float* __restrict__ stats, int npart, int nplanes)
{
  int p = blockIdx.x * 256 + threadIdx.x;
  if (p >= nplanes) return;
  float s = 0.f, q = 0.f;
  for (int j = 0; j < npart; ++j) {
    s += ps[(size_t)p * npart + j];
    q += pss[(size_t)p * npart + j];
  }
  stats[p] = s;
  stats[nplanes + p] = q;
}

template <typename T>
__global__ __launch_bounds__(256) void k_simam_t(
    T* __restrict__ buf, const float* __restrict__ stats, int nplanes)
{
  const int p = blockIdx.x, tid = threadIdx.x;
  T* base = buf + (size_t)p * 8192;
  const float s = stats[p], ss = stats[nplanes + p];
#pragma unroll 4
  for (int i = 0; i < 32; ++i) {
    int idx = tid + i * 256;
    float v = ld1(base + idx);
    st1(base + idx, simam_elem(v, s, ss));
  }
}

// --------------------------- CNN stage 2 (unchanged) -----------------------
template <typename ZT>
__global__ __launch_bounds__(256) void k_conv2(
    const u16* __restrict__ y1u,
    const float* __restrict__ w2a, const float* __restrict__ b2a,
    const float* __restrict__ g2a, const float* __restrict__ bb2a,
    const float* __restrict__ m2a, const float* __restrict__ v2a,
    const float* __restrict__ w2b, const float* __restrict__ b2b,
    const float* __restrict__ g2b, const float* __restrict__ bb2b,
    const float* __restrict__ m2b, const float* __restrict__ v2b,
    ZT* __restrict__ z, float* __restrict__ ps2, float* __restrict__ pss2)
{
  __shared__ float y1s[32][4][66];
  __shared__ float a2[64][4][66];
  __shared__ float sA2a[64], sT2a[64], sA2b[64], sT2b[64];
  const int tid = threadIdx.x;
  const int t0 = blockIdx.x * 2, b = blockIdx.y;
  if (tid < 64) {
    float sa = g2a[tid] * rsqrtf(v2a[tid] + EPSBN);
    sA2a[tid] = sa;
    sT2a[tid] = (b2a[tid] - m2a[tid]) * sa + bb2a[tid];
    float sb = g2b[tid] * rsqrtf(v2b[tid] + EPSBN);
    sA2b[tid] = sb;
    sT2b[tid] = (b2b[tid] - m2b[tid]) * sb + bb2b[tid];
  }
  for (int i = tid; i < 32 * 4 * 66; i += 256) {
    int c1 = i / 264;
    int rr = i - c1 * 264;
    int r = rr / 66, cc = rr - r * 66;
    int t = t0 + r - 1, dd = cc - 1;
    float v = 0.f;
    if (t >= 0 && t < 128 && dd >= 0 && dd < 64)
      v = b2f(y1u[(size_t)(b * 32 + c1) * 8192 + t * 64 + dd]);
    y1s[c1][r][cc] = v;
  }
  __syncthreads();
  const int lane = tid & 63;
  const int c2base = __builtin_amdgcn_readfirstlane((int)(tid >> 6)) * 16;
#pragma unroll 1
  for (int i = 0; i < 16; ++i) {
    const int c2 = c2base + i;
    const float* wp = w2a + c2 * 32;  // uniform
    const float scl = sA2a[c2], off = sT2a[c2];
#pragma unroll 1
    for (int r = 0; r < 4; ++r) {
      for (int cc = lane; cc < 66; cc += 64) {
        float acc = 0.f;
#pragma unroll
        for (int c1 = 0; c1 < 32; ++c1) acc += y1s[c1][r][cc] * wp[c1];
        int t = t0 + r - 1, dd = cc - 1;
        float val = 0.f;
        if (t >= 0 && t < 128 && dd >= 0 && dd < 64)
          val = fmaxf(acc * scl + off, 0.f);
        a2[c2][r][cc] = val;
      }
    }
  }
  __syncthreads();
  const int d = tid & 63;
  const int gq = __builtin_amdgcn_readfirstlane((int)(tid >> 6));
  float acc[16][2];
#pragma unroll
  for (int i = 0; i < 16; ++i) { acc[i][0] = 0.f; acc[i][1] = 0.f; }
#pragma unroll 1
  for (int c1 = 0; c1 < 64; ++c1) {
    float a00 = a2[c1][0][d], a01 = a2[c1][0][d + 1], a02 = a2[c1][0][d + 2];
    float a10 = a2[c1][1][d], a11 = a2[c1][1][d + 1], a12 = a2[c1][1][d + 2];
    float a20 = a2[c1][2][d], a21 = a2[c1][2][d + 1], a22 = a2[c1][2][d + 2];
    float a30 = a2[c1][3][d], a31 = a2[c1][3][d + 1], a32 = a2[c1][3][d + 2];
#pragma unroll
    for (int i = 0; i < 16; ++i) {
      const float* wp = w2b + (size_t)((gq * 16 + i) * 64 + c1) * 9;  // uniform
      float w0 = wp[0], w1 = wp[1], w2 = wp[2];
      float w3 = wp[3], w4 = wp[4], w5 = wp[5];
      float w6 = wp[6], w7 = wp[7], w8 = wp[8];
      acc[i][0] += a00 * w0 + a01 * w1 + a02 * w2 + a10 * w3 + a11 * w4 +
                   a12 * w5 + a20 * w6 + a21 * w7 + a22 * w8;
      acc[i][1] += a10 * w0 + a11 * w1 + a12 * w2 + a20 * w3 + a21 * w4 +
                   a22 * w5 + a30 * w6 + a31 * w7 + a32 * w8;
    }
  }
#pragma unroll
  for (int i = 0; i < 16; ++i) {
    int c2 = gq * 16 + i;
    float sc = sA2b[c2], tb = sT2b[c2];
    float v0 = fmaxf(acc[i][0] * sc + tb, 0.f);
    float v1 = fmaxf(acc[i][1] * sc + tb, 0.f);
    size_t ob = (size_t)(b * 64 + c2) * 8192 + (size_t)t0 * 64 + d;
    st1(z + ob, v0);
    st1(z + ob + 64, v1);
    float s = v0 + v1, q = v0 * v0 + v1 * v1;
#pragma unroll
    for (int off = 32; off; off >>= 1) {
      s += __shfl_down(s, off);
      q += __shfl_down(q, off);
    }
    if (lane == 0) {
      ps2[(size_t)((b * 64 + c2) << 6) + blockIdx.x] = s;
      pss2[(size_t)((b * 64 + c2) << 6) + blockIdx.x] = q;
    }
  }
}

// ------------- weight conversion (f32 -> f16, lane-interleaved) ------------
// dst[tile][kc][ln][j] = src[tile*TN + ln][kc*4 + j], tile width TN rows of
// K columns. In-kernel load for row r, col k (k%4==0):
//   base + (r/TN)*(TN*K) + k*TN + (r%TN)*4   -> one contiguous wave load.
__global__ __launch_bounds__(256) void k_w16t(
    const float* __restrict__ s, f16* __restrict__ d, int N, int K, int TN)
{
  const int total = N * K;
  const int tk = TN * K, t4 = TN * 4;
  for (int i = blockIdx.x * 256 + threadIdx.x; i < total;
       i += gridDim.x * 256) {
    int tile = i / tk;
    int rem = i - tile * tk;
    int kc = rem / t4;
    int r2 = rem - kc * t4;
    int ln = r2 >> 2, j = r2 & 3;
    d[i] = (f16)s[(size_t)(tile * TN + ln) * K + kc * 4 + j];
  }
}

// --------------------------- LSTM kernels ----------------------------------
__global__ __launch_bounds__(256) void k_hfin(
    const float* __restrict__ gslab, const float* __restrict__ bih,
    const float* __restrict__ bhh, float* __restrict__ h, float* __restrict__ c,
    int is_t0)
{
  const int i = blockIdx.x * 256 + threadIdx.x;
  const int b = i >> 8, k = i & 255;
  if (is_t0) { h[i] = 0.f; c[i] = 0.f; return; }
  float gi = bih[k] + bhh[k];
  float gf = bih[k + 256] + bhh[k + 256];
  float gg = bih[k + 512] + bhh[k + 512];
  float go = bih[k + 768] + bhh[k + 768];
#pragma unroll 1
  for (int s = 0; s < 17; ++s) {
    const float* gs = gslab + (size_t)s * 131072 + b * 1024;
    gi += gs[k]; gf += gs[k + 256]; gg += gs[k + 512]; go += gs[k + 768];
  }
  float cn = sigf(gf) * c[i] + sigf(gi) * tanhf(gg);
  c[i] = cn;
  h[i] = sigf(go) * tanhf(cn);
}

// q stage; qW is TILED (64-row tiles): tile = blockIdx.x.
template <typename XT, bool FUSE>
__global__ __launch_bounds__(256) void k_q(
    const f16* __restrict__ qW, const float* __restrict__ qb,
    const float* __restrict__ hmsrc,
    const float* __restrict__ rslab, const float* __restrict__ rbv,
    float* __restrict__ hmout,
    const XT* __restrict__ xin, int xin_bstride, float* __restrict__ xm)
{
  __shared__ float hms[32][256];
  const int tid = threadIdx.x;
  const int n0 = blockIdx.x * 64, b0 = blockIdx.y * 32;
  if (!FUSE) {
    for (int i = tid; i < 32 * 256; i += 256) {
      int bl = i >> 8, k = i & 255;
      hms[bl][k] = hmsrc[(b0 + bl) * 256 + k];
    }
  } else {
    for (int i = tid; i < 2048; i += 256) {  // float4 granularity
      int bl = i >> 6, c4 = (i & 63) << 2;
      int b = b0 + bl;
      float4 acc = *(const float4*)(rbv + c4);
#pragma unroll
      for (int ss = 0; ss < 8; ++ss) {
        float4 rv = *(const float4*)(rslab + (size_t)((ss * 128 + b) << 8) + c4);
        acc.x += rv.x; acc.y += rv.y; acc.z += rv.z; acc.w += rv.w;
      }
      float4 sv = *(const float4*)(hmsrc + (b << 8) + c4);
      float4 o;
      o.x = 2.0f * sigf(acc.x) * sv.x;
      o.y = 2.0f * sigf(acc.y) * sv.y;
      o.z = 2.0f * sigf(acc.z) * sv.z;
      o.w = 2.0f * sigf(acc.w) * sv.w;
      *(float4*)&hms[bl][c4] = o;
    }
  }
  __syncthreads();
  if (FUSE && blockIdx.x == 0) {
    for (int i = tid; i < 8192; i += 256)
      hmout[(b0 << 8) + i] = hms[i >> 8][i & 255];
  }
  const int ln = tid & 63, bg = tid >> 6;
  const int n = n0 + ln;
  float acc[8];
#pragma unroll
  for (int j = 0; j < 8; ++j) acc[j] = 0.f;
  const f16* wt = qW + (size_t)blockIdx.x * (64 * 256);  // tiled layout
  for (int k = 0; k < 256; k += 4) {
    float w[4];
    ldh4(wt + k * 64 + ln * 4, w);  // contiguous 512B per wave
#pragma unroll
    for (int j = 0; j < 8; ++j) {
      float4 hv = *(const float4*)&hms[bg * 8 + j][k];
      acc[j] += w[0] * hv.x + w[1] * hv.y + w[2] * hv.z + w[3] * hv.w;
    }
  }
  float bias = qb[n];
#pragma unroll
  for (int j = 0; j < 8; ++j) {
    int b = b0 + bg * 8 + j;
    float xv = ld1(xin + (size_t)b * xin_bstride + n);
    xm[(size_t)b * 4096 + n] = 2.0f * sigf(acc[j] + bias) * xv;
  }
}

// r stage; rW is TILED (32-row tiles): tile = blockIdx.x.
__global__ __launch_bounds__(256) void k_r(
    const f16* __restrict__ rW, const float* __restrict__ xm,
    float* __restrict__ rslab)
{
  __shared__ float xms[32][128];
  const int tid = threadIdx.x;
  const int n0 = blockIdx.x * 32, b0 = blockIdx.y * 32, ks = blockIdx.z;
  const int ln = tid & 31, bg = tid >> 5;
  const int n = n0 + ln;
  float acc[4] = {0.f, 0.f, 0.f, 0.f};
  const f16* wt = rW + (size_t)blockIdx.x * (32 * 4096);  // tiled layout
#pragma unroll 1
  for (int sub = 0; sub < 4; ++sub) {
    const int kbase = ks * 512 + sub * 128;
    __syncthreads();
    for (int i = tid; i < 1024; i += 256) {
      int row = i >> 5, col4 = i & 31;
      *(float4*)&xms[row][col4 * 4] =
          *(const float4*)(xm + (size_t)(b0 + row) * 4096 + kbase + col4 * 4);
    }
    __syncthreads();
    for (int k = 0; k < 128; k += 4) {
      float w[4];
      ldh4(wt + (size_t)(kbase + k) * 32 + ln * 4, w);  // contiguous 256B
#pragma unroll
      for (int j = 0; j < 4; ++j) {
        float4 xv = *(const float4*)&xms[bg * 4 + j][k];
        acc[j] += w[0] * xv.x + w[1] * xv.y + w[2] * xv.z + w[3] * xv.w;
      }
    }
  }
#pragma unroll
  for (int j = 0; j < 4; ++j)
    rslab[(size_t)(ks * 128 + b0 + bg * 4 + j) * 256 + n] = acc[j];
}

// merged gates kernel: grid (4,4,20). wih/whh TILED (64-row tiles).
//  ks<16 : wih K-slice -> gslab[ks]; gate g rows g*256+jt*64.. = tile g*4+jt
//  ks>=16: whh part (nt=(ks-16)*4+bx), hmfin2 fused -> gslab[16]
__global__ __launch_bounds__(256) void k_gw(
    const f16* __restrict__ wih, const f16* __restrict__ whh,
    const float* __restrict__ xm, const float* __restrict__ rslab,
    const float* __restrict__ rb2, const float* __restrict__ hmB,
    float* __restrict__ gslab)
{
  __shared__ float sm[32 * 256];  // 32 KB shared by both branches
  const int tid = threadIdx.x;
  const int ks = blockIdx.z;
  if (ks < 16) {
    float (*xms)[128] = (float (*)[128])sm;
    const int jt = blockIdx.x, b0 = blockIdx.y * 32;
    const int ln = tid & 63, bg = tid >> 6;
    const int nj = jt * 64 + ln;
    float acc[8][4];
#pragma unroll
    for (int j = 0; j < 8; ++j)
#pragma unroll
      for (int g = 0; g < 4; ++g) acc[j][g] = 0.f;
    const f16* w0 = wih + (size_t)(0 * 4 + jt) * (64 * 4096);  // tiled
    const f16* w1 = wih + (size_t)(1 * 4 + jt) * (64 * 4096);
    const f16* w2 = wih + (size_t)(2 * 4 + jt) * (64 * 4096);
    const f16* w3 = wih + (size_t)(3 * 4 + jt) * (64 * 4096);
#pragma unroll 1
    for (int sub = 0; sub < 2; ++sub) {
      const int kbase = ks * 256 + sub * 128;
      __syncthreads();
      for (int i = tid; i < 1024; i += 256) {
        int row = i >> 5, col4 = i & 31;
        *(float4*)&xms[row][col4 * 4] =
            *(const float4*)(xm + (size_t)(b0 + row) * 4096 + kbase + col4 * 4);
      }
      __syncthreads();
      for (int k = 0; k < 128; k += 4) {
        float wa[4], wb[4], wc[4], wd[4];
        const size_t ko = (size_t)(kbase + k) * 64 + ln * 4;
        ldh4(w0 + ko, wa);  // each: contiguous 512B per wave
        ldh4(w1 + ko, wb);
        ldh4(w2 + ko, wc);
        ldh4(w3 + ko, wd);
#pragma unroll
        for (int j = 0; j < 8; ++j) {
          float4 xv = *(const float4*)&xms[bg * 8 + j][k];
          acc[j][0] += wa[0] * xv.x + wa[1] * xv.y + wa[2] * xv.z + wa[3] * xv.w;
          acc[j][1] += wb[0] * xv.x + wb[1] * xv.y + wb[2] * xv.z + wb[3] * xv.w;
          acc[j][2] += wc[0] * xv.x + wc[1] * xv.y + wc[2] * xv.z + wc[3] * xv.w;
          acc[j][3] += wd[0] * xv.x + wd[1] * xv.y + wd[2] * xv.z + wd[3] * xv.w;
        }
      }
    }
#pragma unroll
    for (int j = 0; j < 8; ++j) {
      size_t base = (size_t)ks * 131072 + (size_t)(b0 + bg * 8 + j) * 1024 + nj;
      gslab[base]       = acc[j][0];
      gslab[base + 256] = acc[j][1];
      gslab[base + 512] = acc[j][2];
      gslab[base + 768] = acc[j][3];
    }
  } else {
    float (*hms)[256] = (float (*)[256])sm;
    const int nt = (ks - 16) * 4 + blockIdx.x;  // 0..15
    const int b0 = blockIdx.y * 32;
    for (int i = tid; i < 2048; i += 256) {  // fused hmfin2 (float4)
      int bl = i >> 6, c4 = (i & 63) << 2;
      int b = b0 + bl;
      float4 acc = *(const float4*)(rb2 + c4);
#pragma unroll
      for (int ss = 0; ss < 8; ++ss) {
        float4 rv = *(const float4*)(rslab + (size_t)((ss * 128 + b) << 8) + c4);
        acc.x += rv.x; acc.y += rv.y; acc.z += rv.z; acc.w += rv.w;
      }
      float4 sv = *(const float4*)(hmB + (b << 8) + c4);
      float4 o;
      o.x = 2.0f * sigf(acc.x) * sv.x;
      o.y = 2.0f * sigf(acc.y) * sv.y;
      o.z = 2.0f * sigf(acc.z) * sv.z;
      o.w = 2.0f * sigf(acc.w) * sv.w;
      *(float4*)&hms[bl][c4] = o;
    }
    __syncthreads();
    const int ln = tid & 63, bg = tid >> 6;
    const int n = nt * 64 + ln;
    float acc[8];
#pragma unroll
    for (int j = 0; j < 8; ++j) acc[j] = 0.f;
    const f16* wt = whh + (size_t)nt * (64 * 256);  // tiled layout
    for (int k = 0; k < 256; k += 4) {
      float w[4];
      ldh4(wt + k * 64 + ln * 4, w);  // contiguous 512B per wave
#pragma unroll
      for (int j = 0; j < 8; ++j) {
        float4 hv = *(const float4*)&hms[bg * 8 + j][k];
        acc[j] += w[0] * hv.x + w[1] * hv.y + w[2] * hv.z + w[3] * hv.w;
      }
    }
#pragma unroll
    for (int j = 0; j < 8; ++j)
      gslab[(size_t)16 * 131072 + (size_t)(b0 + bg * 8 + j) * 1024 + n] = acc[j];
  }
}

__global__ __launch_bounds__(256) void k_fc(
    const float* __restrict__ h, const float* __restrict__ fcw,
    const float* __restrict__ fcb, float* __restrict__ out)
{
  __shared__ float hs[256];
  const int tid = threadIdx.x, b = blockIdx.x;
  hs[tid] = h[b * 256 + tid];
  __syncthreads();
  if (tid < 5) {
    float acc = fcb[tid];
    for (int k = 0; k < 256; ++k) acc += hs[k] * fcw[tid * 256 + k];
    out[b * 5 + tid] = acc;
  }
}

// diagnostic: report ws_size (MiB) through the output if workspace too small
__global__ __launch_bounds__(256) void k_report(float* out, float v, int n) {
  int i = blockIdx.x * 256 + threadIdx.x;
  if (i < n) out[i] = v;
}

// ---------------------------------------------------------------------------
struct Net {
  const float *x;
  const float *c1a_w, *c1a_b, *g1a, *b1a, *m1a, *v1a;
  const float *c1b_w, *c1b_b, *g1b, *b1b, *m1b, *v1b;
  const float *c2a_w, *c2a_b, *g2a, *b2a, *m2a, *v2a;
  const float *c2b_w, *c2b_b, *g2b, *b2b, *m2b, *v2b;
  const float *qw[3], *qb[3], *rw[3], *rb[3];
  const float *wih, *whh, *bih, *bhh, *fcw, *fcb;
};

template <typename ZT>
static void run_all(const Net& p, ZT* z, u16* y1u, float* scr,
                    float* ps1, float* pss1, float* st1v,
                    float* ps2, float* pss2, float* st2v,
                    float* out, hipStream_t stream)
{
  float* xm    = scr;            // 524,288
  float* h     = scr + 524288;   // 32,768
  float* c     = scr + 557056;   // 32,768
  float* hmA   = scr + 589824;   // 32,768
  float* hmB   = scr + 622592;   // 32,768
  float* rslab = scr + 655360;   // 262,144
  float* gslab = scr + 917504;   // 2,228,224 (17 slabs of 131072)
  f16*   wf    = (f16*)(scr + 3145728);  // 10,747,904 halves (~20.5 MB)

  k_conv1<<<dim3(128, 32), 256, 0, stream>>>(p.x, p.c1a_w, p.c1a_b, p.g1a,
      p.b1a, p.m1a, p.v1a, p.c1b_w, p.c1b_b, p.g1b, p.b1b, p.m1b, p.v1b,
      y1u, ps1, pss1);
  k_red<<<16, 256, 0, stream>>>(ps1, pss1, st1v, 32, 4096);
  k_simam_t<u16><<<4096, 256, 0, stream>>>(y1u, st1v, 4096);
  k_conv2<ZT><<<dim3(64, 128), 256, 0, stream>>>(y1u, p.c2a_w, p.c2a_b, p.g2a,
      p.b2a, p.m2a, p.v2a, p.c2b_w, p.c2b_b, p.g2b, p.b2b, p.m2b, p.v2b,
      z, ps2, pss2);
  k_red<<<32, 256, 0, stream>>>(ps2, pss2, st2v, 64, 8192);
  k_simam_t<ZT><<<8192, 256, 0, stream>>>(z, st2v, 8192);

  // f16 tiled weight conversion (wf overlays the y1u region; stream-ordered
  // after the CNN's last y1u use).
  f16* qw0f = wf;
  f16* qw1f = wf + 1048576;
  f16* qw2f = wf + 2097152;
  f16* rw0f = wf + 3145728;
  f16* rw1f = wf + 4194304;
  f16* rw2f = wf + 5242880;
  f16* wihf = wf + 6291456;
  f16* whhf = wf + 10485760;
  k_w16t<<<1024, 256, 0, stream>>>(p.qw[0], qw0f, 4096, 256, 64);
  k_w16t<<<1024, 256, 0, stream>>>(p.qw[1], qw1f, 4096, 256, 64);
  k_w16t<<<1024, 256, 0, stream>>>(p.qw[2], qw2f, 4096, 256, 64);
  k_w16t<<<1024, 256, 0, stream>>>(p.rw[0], rw0f, 256, 4096, 32);
  k_w16t<<<1024, 256, 0, stream>>>(p.rw[1], rw1f, 256, 4096, 32);
  k_w16t<<<1024, 256, 0, stream>>>(p.rw[2], rw2f, 256, 4096, 32);
  k_w16t<<<4096, 256, 0, stream>>>(p.wih,   wihf, 1024, 4096, 64);
  k_w16t<<<1024, 256, 0, stream>>>(p.whh,   whhf, 1024, 256, 64);

  for (int t = 0; t < 128; ++t) {
    k_hfin<<<128, 256, 0, stream>>>(gslab, p.bih, p.bhh, h, c, t == 0 ? 1 : 0);
    // s=0: hms=h, xin=z
    k_q<ZT, false><<<dim3(64, 4), 256, 0, stream>>>(qw0f, p.qb[0], h,
        nullptr, nullptr, nullptr, z + (size_t)t * 4096, 524288, xm);
    k_r<<<dim3(8, 4, 8), 256, 0, stream>>>(rw0f, xm, rslab);
    // s=1: fused hmfin0 (hm0 = 2sig(rslab+rb0)*h) -> hmA; xin=xm
    k_q<float, true><<<dim3(64, 4), 256, 0, stream>>>(qw1f, p.qb[1], h,
        rslab, p.rb[0], hmA, xm, 4096, xm);
    k_r<<<dim3(8, 4, 8), 256, 0, stream>>>(rw1f, xm, rslab);
    // s=2: fused hmfin1 (hm1 = 2sig(rslab+rb1)*hmA) -> hmB; xin=xm
    k_q<float, true><<<dim3(64, 4), 256, 0, stream>>>(qw2f, p.qb[2], hmA,
        rslab, p.rb[1], hmB, xm, 4096, xm);
    k_r<<<dim3(8, 4, 8), 256, 0, stream>>>(rw2f, xm, rslab);
    // gates: wih (ks<16) + whh with fused hmfin2 (ks>=16)
    k_gw<<<dim3(4, 4, 20), 256, 0, stream>>>(wihf, whhf, xm, rslab,
        p.rb[2], hmB, gslab);
  }
  k_hfin<<<128, 256, 0, stream>>>(gslab, p.bih, p.bhh, h, c, 0);
  k_fc<<<128, 256, 0, stream>>>(h, p.fcw, p.fcb, out);
}

extern "C" void kernel_launch(void* const* d_in, const int* in_sizes, int n_in,
                              void* d_out, int out_size, void* d_ws, size_t ws_size,
                              hipStream_t stream)
{
  (void)in_sizes; (void)n_in;
  Net p;
  p.x = (const float*)d_in[0];
  p.c1a_w = (const float*)d_in[1];  p.c1a_b = (const float*)d_in[2];
  p.g1a = (const float*)d_in[3];    p.b1a = (const float*)d_in[4];
  p.m1a = (const float*)d_in[5];    p.v1a = (const float*)d_in[6];
  p.c1b_w = (const float*)d_in[7];  p.c1b_b = (const float*)d_in[8];
  p.g1b = (const float*)d_in[9];    p.b1b = (const float*)d_in[10];
  p.m1b = (const float*)d_in[11];   p.v1b = (const float*)d_in[12];
  p.c2a_w = (const float*)d_in[13]; p.c2a_b = (const float*)d_in[14];
  p.g2a = (const float*)d_in[15];   p.b2a = (const float*)d_in[16];
  p.m2a = (const float*)d_in[17];   p.v2a = (const float*)d_in[18];
  p.c2b_w = (const float*)d_in[19]; p.c2b_b = (const float*)d_in[20];
  p.g2b = (const float*)d_in[21];   p.b2b = (const float*)d_in[22];
  p.m2b = (const float*)d_in[23];   p.v2b = (const float*)d_in[24];
  for (int i = 0; i < 3; ++i) {
    p.qw[i] = (const float*)d_in[25 + 4 * i];
    p.qb[i] = (const float*)d_in[26 + 4 * i];
    p.rw[i] = (const float*)d_in[27 + 4 * i];
    p.rb[i] = (const float*)d_in[28 + 4 * i];
  }
  p.wih = (const float*)d_in[37]; p.whh = (const float*)d_in[38];
  p.bih = (const float*)d_in[39]; p.bhh = (const float*)d_in[40];
  p.fcw = (const float*)d_in[41]; p.fcb = (const float*)d_in[42];
  float* out = (float*)d_out;
  char* base = (char*)d_ws;

  // z elems = 67,108,864 ; y1 elems = 33,554,432 ; stats block = 6,422,528 B
  const size_t ZB_F32 = 268435456, ZB_BF16 = 134217728, Y1B = 67108864;
  const size_t STATS = 1048576 * 2 + 65536 + 2097152 * 2 + 65536;
  const size_t HI_NEED = ZB_F32 + Y1B + STATS;   // ~326 MiB
  const size_t LO_NEED = ZB_BF16 + Y1B + STATS;  // ~198 MiB

  if (ws_size >= HI_NEED) {
    float* z = (float*)base;
    u16* y1u = (u16*)(base + ZB_F32);
    float* scr = (float*)(base + ZB_F32);  // overlays y1u after conv2 is done
    char* sb = base + ZB_F32 + Y1B;
    run_all<float>(p, z, y1u, scr,
                   (float*)sb, (float*)(sb + 1048576), (float*)(sb + 2097152),
                   (float*)(sb + 2162688), (float*)(sb + 4259840),
                   (float*)(sb + 6356992), out, stream);
  } else if (ws_size >= LO_NEED) {
    u16* z = (u16*)base;
    u16* y1u = (u16*)(base + ZB_BF16);
    float* scr = (float*)(base + ZB_BF16);  // overlays y1u after conv2 is done
    char* sb = base + ZB_BF16 + Y1B;
    run_all<u16>(p, z, y1u, scr,
                 (float*)sb, (float*)(sb + 1048576), (float*)(sb + 2097152),
                 (float*)(sb + 2162688), (float*)(sb + 4259840),
                 (float*)(sb + 6356992), out, stream);
  } else {
    k_report<<<3, 256, 0, stream>>>(out, (float)(ws_size >> 20), out_size);
  }
}

// Round 8
// 31236.343 us; speedup vs baseline: 1.1065x; 1.1065x over previous
//
#include <hip/hip_runtime.h>
#include <math.h>

// ---------------------------------------------------------------------------
// SimAM-CNN + Mogrifier-LSTM (Round 10): round-6 structure (27.8 ms proven,
// linear f16 weights) + 2x grid parallelism in the LSTM matmul kernels.
// Round-7 post-mortem: tiled weights REGRESSED (34.6 ms) — row-major rows
// give free L1 temporal reuse; the real limiter is occupancy (256 blocks =
// 1 wave/SIMD, every L2 stall idles the SIMD). Fix: 16 rows/block instead of
// 32 -> 512-640 blocks = 2-2.5 blocks/CU = 8-10 waves/CU. Same k-order per
// (b,n) dot product -> bit-exact vs round 6 (absmax 2.441e-4).
// ---------------------------------------------------------------------------

typedef unsigned short u16;
typedef _Float16 f16;

#define EPSBN 1e-5f

__device__ __forceinline__ float sigf(float x) { return 1.0f / (1.0f + expf(-x)); }

__device__ __forceinline__ float b2f(u16 u) {
  union { unsigned int i; float f; } v; v.i = ((unsigned int)u) << 16; return v.f;
}
__device__ __forceinline__ u16 f2b(float f) {
  union { float f; unsigned int i; } v; v.f = f;
  unsigned int r = v.i + 0x7FFFu + ((v.i >> 16) & 1u);
  return (u16)(r >> 16);
}

template <typename T> __device__ __forceinline__ float ld1(const T* p);
template <> __device__ __forceinline__ float ld1<float>(const float* p) { return *p; }
template <> __device__ __forceinline__ float ld1<u16>(const u16* p) { return b2f(*p); }
template <typename T> __device__ __forceinline__ void st1(T* p, float v);
template <> __device__ __forceinline__ void st1<float>(float* p, float v) { *p = v; }
template <> __device__ __forceinline__ void st1<u16>(u16* p, float v) { *p = f2b(v); }

__device__ __forceinline__ void ldh4(const f16* p, float* w) {
  union { uint2 u; f16 h[4]; } v; v.u = *(const uint2*)p;
#pragma unroll
  for (int i = 0; i < 4; ++i) w[i] = (float)v.h[i];
}

__device__ __forceinline__ float simam_elem(float xv, float s, float ss) {
  float mu = (s - xv) * (1.0f / 8191.0f);
  float var = (ss - xv * xv - 8191.0f * mu * mu) * (1.0f / 8190.0f);
  float einv = ((xv - mu) * (xv - mu) + 2.0f * var + 0.2f) / (4.0f * (var + 0.1f));
  return xv * sigf(einv);
}

// --------------------------- CNN stage 1 (unchanged) -----------------------
__global__ __launch_bounds__(256) void k_conv1(
    const float* __restrict__ x,
    const float* __restrict__ w1a, const float* __restrict__ b1a,
    const float* __restrict__ g1a, const float* __restrict__ bb1a,
    const float* __restrict__ m1a, const float* __restrict__ v1a,
    const float* __restrict__ w1b, const float* __restrict__ b1b,
    const float* __restrict__ g1b, const float* __restrict__ bb1b,
    const float* __restrict__ m1b, const float* __restrict__ v1b,
    u16* __restrict__ y1u, float* __restrict__ ps1, float* __restrict__ pss1)
{
  __shared__ float xs[6][66];
  __shared__ float a1[32][6][66];
  __shared__ float A1[32], T1[32], S2[32], T2[32];
  __shared__ float reds[4][32], redq[4][32];
  const int tid = threadIdx.x;
  const int b = blockIdx.x, t0 = blockIdx.y * 4;
  if (tid < 32) {
    float s = g1a[tid] * rsqrtf(v1a[tid] + EPSBN);
    A1[tid] = w1a[tid] * s;
    T1[tid] = (b1a[tid] - m1a[tid]) * s + bb1a[tid];
    float s2 = g1b[tid] * rsqrtf(v1b[tid] + EPSBN);
    S2[tid] = s2;
    T2[tid] = (b1b[tid] - m1b[tid]) * s2 + bb1b[tid];
  }
  for (int i = tid; i < 6 * 66; i += 256) {
    int r = i / 66, cc = i - r * 66;
    int t = t0 + r - 1, d = cc - 1;
    float v = 0.f;
    if (t >= 0 && t < 128 && d >= 0 && d < 64) v = x[(b * 128 + t) * 64 + d];
    xs[r][cc] = v;
  }
  __syncthreads();
  for (int i = tid; i < 32 * 6 * 66; i += 256) {
    int c = i / 396;
    int rr = i - c * 396;
    int r = rr / 66, cc = rr - r * 66;
    int t = t0 + r - 1, d = cc - 1;
    float v = 0.f;
    if (t >= 0 && t < 128 && d >= 0 && d < 64)
      v = fmaxf(xs[r][cc] * A1[c] + T1[c], 0.f);
    a1[c][r][cc] = v;
  }
  __syncthreads();
  const int d = tid & 63, tq = tid >> 6, lane = tid & 63;
  float acc[32];
#pragma unroll
  for (int i = 0; i < 32; ++i) acc[i] = 0.f;
#pragma unroll 1
  for (int c1 = 0; c1 < 32; ++c1) {
#pragma unroll
    for (int dt = 0; dt < 3; ++dt) {
      float av0 = a1[c1][tq + dt][d];
      float av1 = a1[c1][tq + dt][d + 1];
      float av2 = a1[c1][tq + dt][d + 2];
#pragma unroll
      for (int c2 = 0; c2 < 32; ++c2) {
        const float* wp = w1b + ((c2 * 32 + c1) * 3 + dt) * 3;  // uniform
        acc[c2] += av0 * wp[0] + av1 * wp[1] + av2 * wp[2];
      }
    }
  }
  const size_t ob = (size_t)b * 32 * 8192 + (size_t)(t0 + tq) * 64 + d;
#pragma unroll
  for (int c2 = 0; c2 < 32; ++c2) {
    float v = fmaxf(acc[c2] * S2[c2] + T2[c2], 0.f);
    y1u[ob + (size_t)c2 * 8192] = f2b(v);
    float s = v, q = v * v;
#pragma unroll
    for (int off = 32; off; off >>= 1) {
      s += __shfl_down(s, off);
      q += __shfl_down(q, off);
    }
    if (lane == 0) { reds[tq][c2] = s; redq[tq][c2] = q; }
  }
  __syncthreads();
  if (tid < 32) {
    float s = (reds[0][tid] + reds[1][tid]) + (reds[2][tid] + reds[3][tid]);
    float q = (redq[0][tid] + redq[1][tid]) + (redq[2][tid] + redq[3][tid]);
    ps1[(size_t)((b * 32 + tid) << 5) + blockIdx.y] = s;
    pss1[(size_t)((b * 32 + tid) << 5) + blockIdx.y] = q;
  }
}

__global__ __launch_bounds__(256) void k_red(
    const float* __restrict__ ps, const float* __restrict__ pss,
    float* __restrict__ stats, int npart, int nplanes)
{
  int p = blockIdx.x * 256 + threadIdx.x;
  if (p >= nplanes) return;
  float s = 0.f, q = 0.f;
  for (int j = 0; j < npart; ++j) {
    s += ps[(size_t)p * npart + j];
    q += pss[(size_t)p * npart + j];
  }
  stats[p] = s;
  stats[nplanes + p] = q;
}

template <typename T>
__global__ __launch_bounds__(256) void k_simam_t(
    T* __restrict__ buf, const float* __restrict__ stats, int nplanes)
{
  const int p = blockIdx.x, tid = threadIdx.x;
  T* base = buf + (size_t)p * 8192;
  const float s = stats[p], ss = stats[nplanes + p];
#pragma unroll 4
  for (int i = 0; i < 32; ++i) {
    int idx = tid + i * 256;
    float v = ld1(base + idx);
    st1(base + idx, simam_elem(v, s, ss));
  }
}

// --------------------------- CNN stage 2 (unchanged) -----------------------
template <typename ZT>
__global__ __launch_bounds__(256) void k_conv2(
    const u16* __restrict__ y1u,
    const float* __restrict__ w2a, const float* __restrict__ b2a,
    const float* __restrict__ g2a, const float* __restrict__ bb2a,
    const float* __restrict__ m2a, const float* __restrict__ v2a,
    const float* __restrict__ w2b, const float* __restrict__ b2b,
    const float* __restrict__ g2b, const float* __restrict__ bb2b,
    const float* __restrict__ m2b, const float* __restrict__ v2b,
    ZT* __restrict__ z, float* __restrict__ ps2, float* __restrict__ pss2)
{
  __shared__ float y1s[32][4][66];
  __shared__ float a2[64][4][66];
  __shared__ float sA2a[64], sT2a[64], sA2b[64], sT2b[64];
  const int tid = threadIdx.x;
  const int t0 = blockIdx.x * 2, b = blockIdx.y;
  if (tid < 64) {
    float sa = g2a[tid] * rsqrtf(v2a[tid] + EPSBN);
    sA2a[tid] = sa;
    sT2a[tid] = (b2a[tid] - m2a[tid]) * sa + bb2a[tid];
    float sb = g2b[tid] * rsqrtf(v2b[tid] + EPSBN);
    sA2b[tid] = sb;
    sT2b[tid] = (b2b[tid] - m2b[tid]) * sb + bb2b[tid];
  }
  for (int i = tid; i < 32 * 4 * 66; i += 256) {
    int c1 = i / 264;
    int rr = i - c1 * 264;
    int r = rr / 66, cc = rr - r * 66;
    int t = t0 + r - 1, dd = cc - 1;
    float v = 0.f;
    if (t >= 0 && t < 128 && dd >= 0 && dd < 64)
      v = b2f(y1u[(size_t)(b * 32 + c1) * 8192 + t * 64 + dd]);
    y1s[c1][r][cc] = v;
  }
  __syncthreads();
  const int lane = tid & 63;
  const int c2base = __builtin_amdgcn_readfirstlane((int)(tid >> 6)) * 16;
#pragma unroll 1
  for (int i = 0; i < 16; ++i) {
    const int c2 = c2base + i;
    const float* wp = w2a + c2 * 32;  // uniform
    const float scl = sA2a[c2], off = sT2a[c2];
#pragma unroll 1
    for (int r = 0; r < 4; ++r) {
      for (int cc = lane; cc < 66; cc += 64) {
        float acc = 0.f;
#pragma unroll
        for (int c1 = 0; c1 < 32; ++c1) acc += y1s[c1][r][cc] * wp[c1];
        int t = t0 + r - 1, dd = cc - 1;
        float val = 0.f;
        if (t >= 0 && t < 128 && dd >= 0 && dd < 64)
          val = fmaxf(acc * scl + off, 0.f);
        a2[c2][r][cc] = val;
      }
    }
  }
  __syncthreads();
  const int d = tid & 63;
  const int gq = __builtin_amdgcn_readfirstlane((int)(tid >> 6));
  float acc[16][2];
#pragma unroll
  for (int i = 0; i < 16; ++i) { acc[i][0] = 0.f; acc[i][1] = 0.f; }
#pragma unroll 1
  for (int c1 = 0; c1 < 64; ++c1) {
    float a00 = a2[c1][0][d], a01 = a2[c1][0][d + 1], a02 = a2[c1][0][d + 2];
    float a10 = a2[c1][1][d], a11 = a2[c1][1][d + 1], a12 = a2[c1][1][d + 2];
    float a20 = a2[c1][2][d], a21 = a2[c1][2][d + 1], a22 = a2[c1][2][d + 2];
    float a30 = a2[c1][3][d], a31 = a2[c1][3][d + 1], a32 = a2[c1][3][d + 2];
#pragma unroll
    for (int i = 0; i < 16; ++i) {
      const float* wp = w2b + (size_t)((gq * 16 + i) * 64 + c1) * 9;  // uniform
      float w0 = wp[0], w1 = wp[1], w2 = wp[2];
      float w3 = wp[3], w4 = wp[4], w5 = wp[5];
      float w6 = wp[6], w7 = wp[7], w8 = wp[8];
      acc[i][0] += a00 * w0 + a01 * w1 + a02 * w2 + a10 * w3 + a11 * w4 +
                   a12 * w5 + a20 * w6 + a21 * w7 + a22 * w8;
      acc[i][1] += a10 * w0 + a11 * w1 + a12 * w2 + a20 * w3 + a21 * w4 +
                   a22 * w5 + a30 * w6 + a31 * w7 + a32 * w8;
    }
  }
#pragma unroll
  for (int i = 0; i < 16; ++i) {
    int c2 = gq * 16 + i;
    float sc = sA2b[c2], tb = sT2b[c2];
    float v0 = fmaxf(acc[i][0] * sc + tb, 0.f);
    float v1 = fmaxf(acc[i][1] * sc + tb, 0.f);
    size_t ob = (size_t)(b * 64 + c2) * 8192 + (size_t)t0 * 64 + d;
    st1(z + ob, v0);
    st1(z + ob + 64, v1);
    float s = v0 + v1, q = v0 * v0 + v1 * v1;
#pragma unroll
    for (int off = 32; off; off >>= 1) {
      s += __shfl_down(s, off);
      q += __shfl_down(q, off);
    }
    if (lane == 0) {
      ps2[(size_t)((b * 64 + c2) << 6) + blockIdx.x] = s;
      pss2[(size_t)((b * 64 + c2) << 6) + blockIdx.x] = q;
    }
  }
}

// --------------------- weight conversion (f32 -> f16) ----------------------
__global__ __launch_bounds__(256) void k_w16(const float* __restrict__ s,
                                             f16* __restrict__ d, int n) {
  for (int i = blockIdx.x * 256 + threadIdx.x; i < n; i += gridDim.x * 256)
    d[i] = (f16)s[i];
}

// --------------------------- LSTM kernels ----------------------------------
__global__ __launch_bounds__(256) void k_hfin(
    const float* __restrict__ gslab, const float* __restrict__ bih,
    const float* __restrict__ bhh, float* __restrict__ h, float* __restrict__ c,
    int is_t0)
{
  const int i = blockIdx.x * 256 + threadIdx.x;
  const int b = i >> 8, k = i & 255;
  if (is_t0) { h[i] = 0.f; c[i] = 0.f; return; }
  float gi = bih[k] + bhh[k];
  float gf = bih[k + 256] + bhh[k + 256];
  float gg = bih[k + 512] + bhh[k + 512];
  float go = bih[k + 768] + bhh[k + 768];
#pragma unroll 1
  for (int s = 0; s < 17; ++s) {
    const float* gs = gslab + (size_t)s * 131072 + b * 1024;
    gi += gs[k]; gf += gs[k + 256]; gg += gs[k + 512]; go += gs[k + 768];
  }
  float cn = sigf(gf) * c[i] + sigf(gi) * tanhf(gg);
  c[i] = cn;
  h[i] = sigf(go) * tanhf(cn);
}

// q stage, 16 rows/block (grid (64,8) = 512 blocks, ~2 blocks/CU).
// FUSE: hms <- 2*sig(rbv + sum rslab[ss<8]) * hmsrc (bit-exact hmfin);
// blockIdx.x==0 blocks materialize hms -> hmout.
template <typename XT, bool FUSE>
__global__ __launch_bounds__(256) void k_q(
    const f16* __restrict__ qW, const float* __restrict__ qb,
    const float* __restrict__ hmsrc,
    const float* __restrict__ rslab, const float* __restrict__ rbv,
    float* __restrict__ hmout,
    const XT* __restrict__ xin, int xin_bstride, float* __restrict__ xm)
{
  __shared__ float hms[16][256];
  const int tid = threadIdx.x;
  const int n0 = blockIdx.x * 64, b0 = blockIdx.y * 16;
  if (!FUSE) {
    for (int i = tid; i < 16 * 256; i += 256) {
      int bl = i >> 8, k = i & 255;
      hms[bl][k] = hmsrc[(b0 + bl) * 256 + k];
    }
  } else {
    for (int i = tid; i < 1024; i += 256) {  // 16 rows x 64 float4
      int bl = i >> 6, c4 = (i & 63) << 2;
      int b = b0 + bl;
      float4 acc = *(const float4*)(rbv + c4);
#pragma unroll
      for (int ss = 0; ss < 8; ++ss) {
        float4 rv = *(const float4*)(rslab + (size_t)((ss * 128 + b) << 8) + c4);
        acc.x += rv.x; acc.y += rv.y; acc.z += rv.z; acc.w += rv.w;
      }
      float4 sv = *(const float4*)(hmsrc + (b << 8) + c4);
      float4 o;
      o.x = 2.0f * sigf(acc.x) * sv.x;
      o.y = 2.0f * sigf(acc.y) * sv.y;
      o.z = 2.0f * sigf(acc.z) * sv.z;
      o.w = 2.0f * sigf(acc.w) * sv.w;
      *(float4*)&hms[bl][c4] = o;
    }
  }
  __syncthreads();
  if (FUSE && blockIdx.x == 0) {
    for (int i = tid; i < 4096; i += 256)
      hmout[(b0 << 8) + i] = hms[i >> 8][i & 255];
  }
  const int n = n0 + (tid & 63), bg = tid >> 6;  // bg 0..3 -> rows bg*4..+4
  float acc[4];
#pragma unroll
  for (int j = 0; j < 4; ++j) acc[j] = 0.f;
  const f16* wrow = qW + (size_t)n * 256;
  for (int k = 0; k < 256; k += 4) {
    float w[4];
    ldh4(wrow + k, w);
#pragma unroll
    for (int j = 0; j < 4; ++j) {
      float4 hv = *(const float4*)&hms[bg * 4 + j][k];
      acc[j] += w[0] * hv.x + w[1] * hv.y + w[2] * hv.z + w[3] * hv.w;
    }
  }
  float bias = qb[n];
#pragma unroll
  for (int j = 0; j < 4; ++j) {
    int b = b0 + bg * 4 + j;
    float xv = ld1(xin + (size_t)b * xin_bstride + n);
    xm[(size_t)b * 4096 + n] = 2.0f * sigf(acc[j] + bias) * xv;
  }
}

// r stage, 16 rows/block (grid (8,8,8) = 512 blocks).
__global__ __launch_bounds__(256) void k_r(
    const f16* __restrict__ rW, const float* __restrict__ xm,
    float* __restrict__ rslab)
{
  __shared__ float xms[16][128];
  const int tid = threadIdx.x;
  const int n0 = blockIdx.x * 32, b0 = blockIdx.y * 16, ks = blockIdx.z;
  const int n = n0 + (tid & 31), bg = tid >> 5;  // bg 0..7 -> rows bg*2..+2
  float acc[2] = {0.f, 0.f};
  const f16* wrow = rW + (size_t)n * 4096;
#pragma unroll 1
  for (int sub = 0; sub < 4; ++sub) {
    const int kbase = ks * 512 + sub * 128;
    __syncthreads();
    for (int i = tid; i < 512; i += 256) {  // 16 rows x 32 float4
      int row = i >> 5, col4 = i & 31;
      *(float4*)&xms[row][col4 * 4] =
          *(const float4*)(xm + (size_t)(b0 + row) * 4096 + kbase + col4 * 4);
    }
    __syncthreads();
    for (int k = 0; k < 128; k += 4) {
      float w[4];
      ldh4(wrow + kbase + k, w);
#pragma unroll
      for (int j = 0; j < 2; ++j) {
        float4 xv = *(const float4*)&xms[bg * 2 + j][k];
        acc[j] += w[0] * xv.x + w[1] * xv.y + w[2] * xv.z + w[3] * xv.w;
      }
    }
  }
#pragma unroll
  for (int j = 0; j < 2; ++j)
    rslab[(size_t)(ks * 128 + b0 + bg * 2 + j) * 256 + n] = acc[j];
}

// merged gates kernel, 16 rows/block: grid (4,8,20) = 640 blocks.
//  ks<16 : wih K-slice -> gslab[ks]
//  ks>=16: whh part (nt=(ks-16)*4+bx), hmfin2 fused -> gslab[16]
__global__ __launch_bounds__(256) void k_gw(
    const f16* __restrict__ wih, const f16* __restrict__ whh,
    const float* __restrict__ xm, const float* __restrict__ rslab,
    const float* __restrict__ rb2, const float* __restrict__ hmB,
    float* __restrict__ gslab)
{
  __shared__ float sm[16 * 256];  // 16 KB shared by both branches
  const int tid = threadIdx.x;
  const int ks = blockIdx.z;
  if (ks < 16) {
    float (*xms)[128] = (float (*)[128])sm;
    const int jt = blockIdx.x, b0 = blockIdx.y * 16;
    const int nj = jt * 64 + (tid & 63), bg = tid >> 6;  // rows bg*4..+4
    float acc[4][4];
#pragma unroll
    for (int j = 0; j < 4; ++j)
#pragma unroll
      for (int g = 0; g < 4; ++g) acc[j][g] = 0.f;
    const f16* w0 = wih + (size_t)nj * 4096;
    const f16* w1 = wih + (size_t)(nj + 256) * 4096;
    const f16* w2 = wih + (size_t)(nj + 512) * 4096;
    const f16* w3 = wih + (size_t)(nj + 768) * 4096;
#pragma unroll 1
    for (int sub = 0; sub < 2; ++sub) {
      const int kbase = ks * 256 + sub * 128;
      __syncthreads();
      for (int i = tid; i < 512; i += 256) {  // 16 rows x 32 float4
        int row = i >> 5, col4 = i & 31;
        *(float4*)&xms[row][col4 * 4] =
            *(const float4*)(xm + (size_t)(b0 + row) * 4096 + kbase + col4 * 4);
      }
      __syncthreads();
      for (int k = 0; k < 128; k += 4) {
        float wa[4], wb[4], wc[4], wd[4];
        ldh4(w0 + kbase + k, wa);
        ldh4(w1 + kbase + k, wb);
        ldh4(w2 + kbase + k, wc);
        ldh4(w3 + kbase + k, wd);
#pragma unroll
        for (int j = 0; j < 4; ++j) {
          float4 xv = *(const float4*)&xms[bg * 4 + j][k];
          acc[j][0] += wa[0] * xv.x + wa[1] * xv.y + wa[2] * xv.z + wa[3] * xv.w;
          acc[j][1] += wb[0] * xv.x + wb[1] * xv.y + wb[2] * xv.z + wb[3] * xv.w;
          acc[j][2] += wc[0] * xv.x + wc[1] * xv.y + wc[2] * xv.z + wc[3] * xv.w;
          acc[j][3] += wd[0] * xv.x + wd[1] * xv.y + wd[2] * xv.z + wd[3] * xv.w;
        }
      }
    }
#pragma unroll
    for (int j = 0; j < 4; ++j) {
      size_t base = (size_t)ks * 131072 + (size_t)(b0 + bg * 4 + j) * 1024 + nj;
      gslab[base]       = acc[j][0];
      gslab[base + 256] = acc[j][1];
      gslab[base + 512] = acc[j][2];
      gslab[base + 768] = acc[j][3];
    }
  } else {
    float (*hms)[256] = (float (*)[256])sm;
    const int nt = (ks - 16) * 4 + blockIdx.x;  // 0..15
    const int b0 = blockIdx.y * 16;
    for (int i = tid; i < 1024; i += 256) {  // fused hmfin2, 16 rows x 64 f4
      int bl = i >> 6, c4 = (i & 63) << 2;
      int b = b0 + bl;
      float4 acc = *(const float4*)(rb2 + c4);
#pragma unroll
      for (int ss = 0; ss < 8; ++ss) {
        float4 rv = *(const float4*)(rslab + (size_t)((ss * 128 + b) << 8) + c4);
        acc.x += rv.x; acc.y += rv.y; acc.z += rv.z; acc.w += rv.w;
      }
      float4 sv = *(const float4*)(hmB + (b << 8) + c4);
      float4 o;
      o.x = 2.0f * sigf(acc.x) * sv.x;
      o.y = 2.0f * sigf(acc.y) * sv.y;
      o.z = 2.0f * sigf(acc.z) * sv.z;
      o.w = 2.0f * sigf(acc.w) * sv.w;
      *(float4*)&hms[bl][c4] = o;
    }
    __syncthreads();
    const int n = nt * 64 + (tid & 63), bg = tid >> 6;  // rows bg*4..+4
    float acc[4];
#pragma unroll
    for (int j = 0; j < 4; ++j) acc[j] = 0.f;
    const f16* wrow = whh + (size_t)n * 256;
    for (int k = 0; k < 256; k += 4) {
      float w[4];
      ldh4(wrow + k, w);
#pragma unroll
      for (int j = 0; j < 4; ++j) {
        float4 hv = *(const float4*)&hms[bg * 4 + j][k];
        acc[j] += w[0] * hv.x + w[1] * hv.y + w[2] * hv.z + w[3] * hv.w;
      }
    }
#pragma unroll
    for (int j = 0; j < 4; ++j)
      gslab[(size_t)16 * 131072 + (size_t)(b0 + bg * 4 + j) * 1024 + n] = acc[j];
  }
}

__global__ __launch_bounds__(256) void k_fc(
    const float* __restrict__ h, const float* __restrict__ fcw,
    const float* __restrict__ fcb, float* __restrict__ out)
{
  __shared__ float hs[256];
  const int tid = threadIdx.x, b = blockIdx.x;
  hs[tid] = h[b * 256 + tid];
  __syncthreads();
  if (tid < 5) {
    float acc = fcb[tid];
    for (int k = 0; k < 256; ++k) acc += hs[k] * fcw[tid * 256 + k];
    out[b * 5 + tid] = acc;
  }
}

// diagnostic: report ws_size (MiB) through the output if workspace too small
__global__ __launch_bounds__(256) void k_report(float* out, float v, int n) {
  int i = blockIdx.x * 256 + threadIdx.x;
  if (i < n) out[i] = v;
}

// ---------------------------------------------------------------------------
struct Net {
  const float *x;
  const float *c1a_w, *c1a_b, *g1a, *b1a, *m1a, *v1a;
  const float *c1b_w, *c1b_b, *g1b, *b1b, *m1b, *v1b;
  const float *c2a_w, *c2a_b, *g2a, *b2a, *m2a, *v2a;
  const float *c2b_w, *c2b_b, *g2b, *b2b, *m2b, *v2b;
  const float *qw[3], *qb[3], *rw[3], *rb[3];
  const float *wih, *whh, *bih, *bhh, *fcw, *fcb;
};

template <typename ZT>
static void run_all(const Net& p, ZT* z, u16* y1u, float* scr,
                    float* ps1, float* pss1, float* st1v,
                    float* ps2, float* pss2, float* st2v,
                    float* out, hipStream_t stream)
{
  float* xm    = scr;            // 524,288
  float* h     = scr + 524288;   // 32,768
  float* c     = scr + 557056;   // 32,768
  float* hmA   = scr + 589824;   // 32,768
  float* hmB   = scr + 622592;   // 32,768
  float* rslab = scr + 655360;   // 262,144
  float* gslab = scr + 917504;   // 2,228,224 (17 slabs of 131072)
  f16*   wf    = (f16*)(scr + 3145728);  // 10,747,904 halves (~20.5 MB)

  k_conv1<<<dim3(128, 32), 256, 0, stream>>>(p.x, p.c1a_w, p.c1a_b, p.g1a,
      p.b1a, p.m1a, p.v1a, p.c1b_w, p.c1b_b, p.g1b, p.b1b, p.m1b, p.v1b,
      y1u, ps1, pss1);
  k_red<<<16, 256, 0, stream>>>(ps1, pss1, st1v, 32, 4096);
  k_simam_t<u16><<<4096, 256, 0, stream>>>(y1u, st1v, 4096);
  k_conv2<ZT><<<dim3(64, 128), 256, 0, stream>>>(y1u, p.c2a_w, p.c2a_b, p.g2a,
      p.b2a, p.m2a, p.v2a, p.c2b_w, p.c2b_b, p.g2b, p.b2b, p.m2b, p.v2b,
      z, ps2, pss2);
  k_red<<<32, 256, 0, stream>>>(ps2, pss2, st2v, 64, 8192);
  k_simam_t<ZT><<<8192, 256, 0, stream>>>(z, st2v, 8192);

  // f16 weight conversion (wf overlays the y1u region; stream-ordered after
  // the CNN's last y1u use).
  f16* qw0f = wf;
  f16* qw1f = wf + 1048576;
  f16* qw2f = wf + 2097152;
  f16* rw0f = wf + 3145728;
  f16* rw1f = wf + 4194304;
  f16* rw2f = wf + 5242880;
  f16* wihf = wf + 6291456;
  f16* whhf = wf + 10485760;
  k_w16<<<1024, 256, 0, stream>>>(p.qw[0], qw0f, 1048576);
  k_w16<<<1024, 256, 0, stream>>>(p.qw[1], qw1f, 1048576);
  k_w16<<<1024, 256, 0, stream>>>(p.qw[2], qw2f, 1048576);
  k_w16<<<1024, 256, 0, stream>>>(p.rw[0], rw0f, 1048576);
  k_w16<<<1024, 256, 0, stream>>>(p.rw[1], rw1f, 1048576);
  k_w16<<<1024, 256, 0, stream>>>(p.rw[2], rw2f, 1048576);
  k_w16<<<4096, 256, 0, stream>>>(p.wih,   wihf, 4194304);
  k_w16<<<1024, 256, 0, stream>>>(p.whh,   whhf, 262144);

  for (int t = 0; t < 128; ++t) {
    k_hfin<<<128, 256, 0, stream>>>(gslab, p.bih, p.bhh, h, c, t == 0 ? 1 : 0);
    // s=0: hms=h, xin=z
    k_q<ZT, false><<<dim3(64, 8), 256, 0, stream>>>(qw0f, p.qb[0], h,
        nullptr, nullptr, nullptr, z + (size_t)t * 4096, 524288, xm);
    k_r<<<dim3(8, 8, 8), 256, 0, stream>>>(rw0f, xm, rslab);
    // s=1: fused hmfin0 (hm0 = 2sig(rslab+rb0)*h) -> hmA; xin=xm
    k_q<float, true><<<dim3(64, 8), 256, 0, stream>>>(qw1f, p.qb[1], h,
        rslab, p.rb[0], hmA, xm, 4096, xm);
    k_r<<<dim3(8, 8, 8), 256, 0, stream>>>(rw1f, xm, rslab);
    // s=2: fused hmfin1 (hm1 = 2sig(rslab+rb1)*hmA) -> hmB; xin=xm
    k_q<float, true><<<dim3(64, 8), 256, 0, stream>>>(qw2f, p.qb[2], hmA,
        rslab, p.rb[1], hmB, xm, 4096, xm);
    k_r<<<dim3(8, 8, 8), 256, 0, stream>>>(rw2f, xm, rslab);
    // gates: wih (ks<16) + whh with fused hmfin2 (ks>=16)
    k_gw<<<dim3(4, 8, 20), 256, 0, stream>>>(wihf, whhf, xm, rslab,
        p.rb[2], hmB, gslab);
  }
  k_hfin<<<128, 256, 0, stream>>>(gslab, p.bih, p.bhh, h, c, 0);
  k_fc<<<128, 256, 0, stream>>>(h, p.fcw, p.fcb, out);
}

extern "C" void kernel_launch(void* const* d_in, const int* in_sizes, int n_in,
                              void* d_out, int out_size, void* d_ws, size_t ws_size,
                              hipStream_t stream)
{
  (void)in_sizes; (void)n_in;
  Net p;
  p.x = (const float*)d_in[0];
  p.c1a_w = (const float*)d_in[1];  p.c1a_b = (const float*)d_in[2];
  p.g1a = (const float*)d_in[3];    p.b1a = (const float*)d_in[4];
  p.m1a = (const float*)d_in[5];    p.v1a = (const float*)d_in[6];
  p.c1b_w = (const float*)d_in[7];  p.c1b_b = (const float*)d_in[8];
  p.g1b = (const float*)d_in[9];    p.b1b = (const float*)d_in[10];
  p.m1b = (const float*)d_in[11];   p.v1b = (const float*)d_in[12];
  p.c2a_w = (const float*)d_in[13]; p.c2a_b = (const float*)d_in[14];
  p.g2a = (const float*)d_in[15];   p.b2a = (const float*)d_in[16];
  p.m2a = (const float*)d_in[17];   p.v2a = (const float*)d_in[18];
  p.c2b_w = (const float*)d_in[19]; p.c2b_b = (const float*)d_in[20];
  p.g2b = (const float*)d_in[21];   p.b2b = (const float*)d_in[22];
  p.m2b = (const float*)d_in[23];   p.v2b = (const float*)d_in[24];
  for (int i = 0; i < 3; ++i) {
    p.qw[i] = (const float*)d_in[25 + 4 * i];
    p.qb[i] = (const float*)d_in[26 + 4 * i];
    p.rw[i] = (const float*)d_in[27 + 4 * i];
    p.rb[i] = (const float*)d_in[28 + 4 * i];
  }
  p.wih = (const float*)d_in[37]; p.whh = (const float*)d_in[38];
  p.bih = (const float*)d_in[39]; p.bhh = (const float*)d_in[40];
  p.fcw = (const float*)d_in[41]; p.fcb = (const float*)d_in[42];
  float* out = (float*)d_out;
  char* base = (char*)d_ws;

  // z elems = 67,108,864 ; y1 elems = 33,554,432 ; stats block = 6,422,528 B
  const size_t ZB_F32 = 268435456, ZB_BF16 = 134217728, Y1B = 67108864;
  const size_t STATS = 1048576 * 2 + 65536 + 2097152 * 2 + 65536;
  const size_t HI_NEED = ZB_F32 + Y1B + STATS;   // ~326 MiB
  const size_t LO_NEED = ZB_BF16 + Y1B + STATS;  // ~198 MiB

  if (ws_size >= HI_NEED) {
    float* z = (float*)base;
    u16* y1u = (u16*)(base + ZB_F32);
    float* scr = (float*)(base + ZB_F32);  // overlays y1u after conv2 is done
    char* sb = base + ZB_F32 + Y1B;
    run_all<float>(p, z, y1u, scr,
                   (float*)sb, (float*)(sb + 1048576), (float*)(sb + 2097152),
                   (float*)(sb + 2162688), (float*)(sb + 4259840),
                   (float*)(sb + 6356992), out, stream);
  } else if (ws_size >= LO_NEED) {
    u16* z = (u16*)base;
    u16* y1u = (u16*)(base + ZB_BF16);
    float* scr = (float*)(base + ZB_BF16);  // overlays y1u after conv2 is done
    char* sb = base + ZB_BF16 + Y1B;
    run_all<u16>(p, z, y1u, scr,
                 (float*)sb, (float*)(sb + 1048576), (float*)(sb + 2097152),
                 (float*)(sb + 2162688), (float*)(sb + 4259840),
                 (float*)(sb + 6356992), out, stream);
  } else {
    k_report<<<3, 256, 0, stream>>>(out, (float)(ws_size >> 20), out_size);
  }
}